// Round 3
// baseline (856.324 us; speedup 1.0000x reference)
//
#include <hip/hip_runtime.h>
#include <stdint.h>

typedef unsigned short ushort_t;
typedef __attribute__((ext_vector_type(8))) short bf16x8;
typedef __attribute__((ext_vector_type(4))) short s16x4;
typedef __attribute__((ext_vector_type(4))) float f32x4;
typedef __attribute__((ext_vector_type(4))) unsigned short us4;

#define DEV __device__ __forceinline__

DEV ushort_t f2bf(float f) {
    unsigned int u = __float_as_uint(f);
    u += 0x7fffu + ((u >> 16) & 1u);
    return (ushort_t)(u >> 16);
}

DEV void async16(const ushort_t* g, ushort_t* l) {
    __builtin_amdgcn_global_load_lds(
        (const __attribute__((address_space(1))) void*)g,
        (__attribute__((address_space(3))) void*)l,
        16, 0, 0);
}

// ---------------------------------------------------------------------------
// f32 -> bf16 conversion of x and the four weight matrices (one launch).
// ---------------------------------------------------------------------------
__global__ void convert_kernel(const float* __restrict__ x, const float* __restrict__ wq,
                               const float* __restrict__ wk, const float* __restrict__ wv,
                               const float* __restrict__ wo,
                               ushort_t* __restrict__ xb, ushort_t* __restrict__ wqb,
                               ushort_t* __restrict__ wkb, ushort_t* __restrict__ wvb,
                               ushort_t* __restrict__ wob)
{
    const int i = blockIdx.x * 256 + threadIdx.x; // float4 index, 1048576 total
    const float* src; ushort_t* dst; int off;
    if (i < 524288)      { src = x;  dst = xb;  off = i; }
    else if (i < 655360) { src = wq; dst = wqb; off = i - 524288; }
    else if (i < 786432) { src = wk; dst = wkb; off = i - 655360; }
    else if (i < 917504) { src = wv; dst = wvb; off = i - 786432; }
    else                 { src = wo; dst = wob; off = i - 917504; }
    const float4 v = ((const float4*)src)[off];
    us4 o;
    o[0] = f2bf(v.x); o[1] = f2bf(v.y); o[2] = f2bf(v.z); o[3] = f2bf(v.w);
    ((us4*)dst)[off] = o;
}

// ---------------------------------------------------------------------------
// bf16 GEMM: C[M][N] = A[M][K] * B[N][K]^T, 128x128 tile, 4 waves.
// MODE 2: f32 row-major out (unused this round, kept for reference).
// MODE 3: fused QKV projection — B is the concatenated [6144][256] weight;
//   column block routes to q (row-major), k (row-major), or v (transposed
//   [b][h][d][l]).  2048 % 128 == 0 so each block hits exactly one output.
// ---------------------------------------------------------------------------
template <int MODE>
__global__ __launch_bounds__(256, 2) void gemm_bt_kernel(
    const ushort_t* __restrict__ A, const ushort_t* __restrict__ Bm,
    void* __restrict__ C0, void* __restrict__ C1, void* __restrict__ C2,
    int M, int N, int K)
{
    __shared__ ushort_t At[128 * 64];
    __shared__ ushort_t Bt[128 * 64];

    const int tid  = threadIdx.x;
    const int wave = tid >> 6;
    const int lane = tid & 63;
    const int quad = lane >> 4;
    const int l15  = lane & 15;
    const int mhalf = wave >> 1;
    const int nhalf = wave & 1;
    const int m0 = blockIdx.x * 128;
    const int n0 = blockIdx.y * 128;

    f32x4 acc[4][4];
#pragma unroll
    for (int mf = 0; mf < 4; ++mf)
#pragma unroll
        for (int nf = 0; nf < 4; ++nf)
#pragma unroll
            for (int r = 0; r < 4; ++r) acc[mf][nf][r] = 0.f;

    const int crow = (lane & 7) ^ (lane >> 3);

    for (int k0 = 0; k0 < K; k0 += 64) {
        __syncthreads();
#pragma unroll
        for (int t = 0; t < 4; ++t) {
            const int row = wave * 32 + t * 8 + (lane >> 3);
            async16(A + (size_t)(m0 + row) * K + k0 + crow * 8,
                    At + (wave * 32 + t * 8) * 64 + lane * 8);
            async16(Bm + (size_t)(n0 + row) * K + k0 + crow * 8,
                    Bt + (wave * 32 + t * 8) * 64 + lane * 8);
        }
        __syncthreads();
#pragma unroll
        for (int ks = 0; ks < 2; ++ks) {
            bf16x8 af[4], bf[4];
#pragma unroll
            for (int mf = 0; mf < 4; ++mf) {
                const int ml = mhalf * 64 + mf * 16 + l15;
                const int c = (ks * 4 + quad) ^ (ml & 7);
                af[mf] = *(const bf16x8*)(At + ml * 64 + c * 8);
            }
#pragma unroll
            for (int nf = 0; nf < 4; ++nf) {
                const int nl = nhalf * 64 + nf * 16 + l15;
                const int c = (ks * 4 + quad) ^ (nl & 7);
                bf[nf] = *(const bf16x8*)(Bt + nl * 64 + c * 8);
            }
#pragma unroll
            for (int mf = 0; mf < 4; ++mf)
#pragma unroll
                for (int nf = 0; nf < 4; ++nf)
                    acc[mf][nf] = __builtin_amdgcn_mfma_f32_16x16x32_bf16(
                        af[mf], bf[nf], acc[mf][nf], 0, 0, 0);
        }
    }

    if (MODE == 3) {
        const int sel = n0 >> 11;               // 0:q 1:k 2:v
        if (sel == 2) {
#pragma unroll
            for (int mf = 0; mf < 4; ++mf)
#pragma unroll
                for (int nf = 0; nf < 4; ++nf) {
                    const int row = m0 + mhalf * 64 + mf * 16 + quad * 4;
                    const int colv = (n0 - 4096) + nhalf * 64 + nf * 16 + l15;
                    const int b_ = row >> 11, l_ = row & 2047;
                    const int h_ = colv >> 8, d_ = colv & 255;
                    us4 pk;
#pragma unroll
                    for (int r = 0; r < 4; ++r) pk[r] = f2bf(acc[mf][nf][r]);
                    *(us4*)((ushort_t*)C2 +
                            (((size_t)(b_ * 8 + h_) * 256 + d_) * 2048 + l_)) = pk;
                }
        } else {
            ushort_t* dst = sel ? (ushort_t*)C1 : (ushort_t*)C0;
#pragma unroll
            for (int mf = 0; mf < 4; ++mf)
#pragma unroll
                for (int nf = 0; nf < 4; ++nf)
#pragma unroll
                    for (int r = 0; r < 4; ++r) {
                        const int row = m0 + mhalf * 64 + mf * 16 + quad * 4 + r;
                        const int col = (n0 & 2047) + nhalf * 64 + nf * 16 + l15;
                        dst[(size_t)row * 2048 + col] = f2bf(acc[mf][nf][r]);
                    }
        }
    } else {
#pragma unroll
        for (int mf = 0; mf < 4; ++mf)
#pragma unroll
            for (int nf = 0; nf < 4; ++nf)
#pragma unroll
                for (int r = 0; r < 4; ++r) {
                    const int row = m0 + mhalf * 64 + mf * 16 + quad * 4 + r;
                    const int col = n0 + nhalf * 64 + nf * 16 + l15;
                    ((float*)C0)[(size_t)row * N + col] = acc[mf][nf][r];
                }
    }
}

// ---------------------------------------------------------------------------
// Output projection GEMM, 64x128 tile (grid 128x2 = 256 blocks -> all CUs).
// C[8192][256] f32 = ao[8192][2048] * Wo[256][2048]^T
// ---------------------------------------------------------------------------
__global__ __launch_bounds__(256, 4) void gemm_out_kernel(
    const ushort_t* __restrict__ A, const ushort_t* __restrict__ Bm,
    float* __restrict__ C)
{
    __shared__ ushort_t At[64 * 64];    // 8 KB
    __shared__ ushort_t Bt[128 * 64];   // 16 KB

    const int tid  = threadIdx.x;
    const int wave = tid >> 6;
    const int lane = tid & 63;
    const int quad = lane >> 4;
    const int l15  = lane & 15;
    const int mhalf = wave >> 1;
    const int nhalf = wave & 1;
    const int m0 = blockIdx.x * 64;
    const int n0 = blockIdx.y * 128;

    f32x4 acc[2][4];
#pragma unroll
    for (int mf = 0; mf < 2; ++mf)
#pragma unroll
        for (int nf = 0; nf < 4; ++nf)
#pragma unroll
            for (int r = 0; r < 4; ++r) acc[mf][nf][r] = 0.f;

    const int crow = (lane & 7) ^ (lane >> 3);

    for (int k0 = 0; k0 < 2048; k0 += 64) {
        __syncthreads();
#pragma unroll
        for (int t = 0; t < 2; ++t) {
            const int row = wave * 16 + t * 8 + (lane >> 3);
            async16(A + (size_t)(m0 + row) * 2048 + k0 + crow * 8,
                    At + (wave * 16 + t * 8) * 64 + lane * 8);
        }
#pragma unroll
        for (int t = 0; t < 4; ++t) {
            const int row = wave * 32 + t * 8 + (lane >> 3);
            async16(Bm + (size_t)(n0 + row) * 2048 + k0 + crow * 8,
                    Bt + (wave * 32 + t * 8) * 64 + lane * 8);
        }
        __syncthreads();
#pragma unroll
        for (int ks = 0; ks < 2; ++ks) {
            bf16x8 af[2], bf[4];
#pragma unroll
            for (int mf = 0; mf < 2; ++mf) {
                const int ml = mhalf * 32 + mf * 16 + l15;
                const int c = (ks * 4 + quad) ^ (ml & 7);
                af[mf] = *(const bf16x8*)(At + ml * 64 + c * 8);
            }
#pragma unroll
            for (int nf = 0; nf < 4; ++nf) {
                const int nl = nhalf * 64 + nf * 16 + l15;
                const int c = (ks * 4 + quad) ^ (nl & 7);
                bf[nf] = *(const bf16x8*)(Bt + nl * 64 + c * 8);
            }
#pragma unroll
            for (int mf = 0; mf < 2; ++mf)
#pragma unroll
                for (int nf = 0; nf < 4; ++nf)
                    acc[mf][nf] = __builtin_amdgcn_mfma_f32_16x16x32_bf16(
                        af[mf], bf[nf], acc[mf][nf], 0, 0, 0);
        }
    }

#pragma unroll
    for (int mf = 0; mf < 2; ++mf)
#pragma unroll
        for (int nf = 0; nf < 4; ++nf)
#pragma unroll
            for (int r = 0; r < 4; ++r) {
                const int row = m0 + mhalf * 32 + mf * 16 + quad * 4 + r;
                const int col = n0 + nhalf * 64 + nf * 16 + l15;
                C[(size_t)row * 256 + col] = acc[mf][nf][r];
            }
}

// ---------------------------------------------------------------------------
// Pass 1: full-row softmax denominator Z_i = sum_j exp(s_ij/16).
// ---------------------------------------------------------------------------
__global__ __launch_bounds__(256, 4) void pass1_kernel(
    const ushort_t* __restrict__ q_ws, const ushort_t* __restrict__ k_ws,
    float* __restrict__ rz_ws)
{
    __shared__ ushort_t Kt[64 * 256];   // 32 KB, chunk-swizzled
    __shared__ float zred[2][64];

    const float SCALE = 0.0625f;        // 1/sqrt(256)
    const int tid  = threadIdx.x;
    const int wave = tid >> 6;
    const int lane = tid & 63;
    const int quad = lane >> 4;
    const int l15  = lane & 15;
    const int ihalf = wave >> 1;
    const int jhalf = wave & 1;

    const int g  = blockIdx.x;
    const int bh = ((g >> 8) << 3) | (g & 7);
    const int it = (g >> 3) & 31;
    const int b = bh >> 3, h = bh & 7;
    const int i0 = it * 64;

    const size_t qkbase = (size_t)b * 2048 * 2048 + (size_t)h * 256;

    bf16x8 qf[2][8];
#pragma unroll
    for (int ng = 0; ng < 2; ++ng) {
        const int i_l = ihalf * 32 + ng * 16 + l15;
        const ushort_t* qr = q_ws + qkbase + (size_t)(i0 + i_l) * 2048;
#pragma unroll
        for (int ks = 0; ks < 8; ++ks)
            qf[ng][ks] = *(const bf16x8*)(qr + ks * 32 + quad * 8);
    }

    float z[2] = {0.f, 0.f};

    for (int jt = 0; jt < 32; ++jt) {
        const int j0 = jt * 64;
        __syncthreads();
        {
            const ushort_t* kb = k_ws + qkbase + (size_t)j0 * 2048;
#pragma unroll
            for (int t = 0; t < 8; ++t) {
                const int row = wave * 16 + t * 2 + (lane >> 5);
                const int c = (lane & 31) ^ (row & 7);
                async16(kb + (size_t)row * 2048 + c * 8,
                        Kt + (wave * 16 + t * 2) * 256 + lane * 8);
            }
        }
        __syncthreads();

        f32x4 sacc[2][2];
#pragma unroll
        for (int a = 0; a < 2; ++a)
#pragma unroll
            for (int c = 0; c < 2; ++c)
#pragma unroll
                for (int r = 0; r < 4; ++r) sacc[a][c][r] = 0.f;

#pragma unroll
        for (int ks = 0; ks < 8; ++ks) {
            bf16x8 af[2];
#pragma unroll
            for (int mg = 0; mg < 2; ++mg) {
                const int j_l = jhalf * 32 + mg * 16 + l15;
                const int c = (ks * 4 + quad) ^ (j_l & 7);
                af[mg] = *(const bf16x8*)(Kt + j_l * 256 + c * 8);
            }
#pragma unroll
            for (int mg = 0; mg < 2; ++mg)
#pragma unroll
                for (int ng = 0; ng < 2; ++ng)
                    sacc[mg][ng] = __builtin_amdgcn_mfma_f32_16x16x32_bf16(
                        af[mg], qf[ng][ks], sacc[mg][ng], 0, 0, 0);
        }

#pragma unroll
        for (int ng = 0; ng < 2; ++ng)
#pragma unroll
            for (int mg = 0; mg < 2; ++mg)
#pragma unroll
                for (int r = 0; r < 4; ++r)
                    z[ng] += __expf(sacc[mg][ng][r] * SCALE);
    }

#pragma unroll
    for (int ng = 0; ng < 2; ++ng) {
        z[ng] += __shfl_xor(z[ng], 16);
        z[ng] += __shfl_xor(z[ng], 32);
    }
    __syncthreads();
    if (quad == 0) {
#pragma unroll
        for (int ng = 0; ng < 2; ++ng) {
            const int i_l = ihalf * 32 + ng * 16 + l15;
            zred[jhalf][i_l] = z[ng];
        }
    }
    __syncthreads();
    if (tid < 64)
        rz_ws[(size_t)bh * 2048 + i0 + tid] = 1.0f / (zred[0][tid] + zred[1][tid]);
}

// ---------------------------------------------------------------------------
// Pass 2: causal w = exp(p), p = exp(s/16)/Z; PV accumulate; divide by sum(w).
// Wave (ihalf, jhalf): QK quadrant [32 j][32 i]; w staged in a WAVE-PRIVATE
// 2 KB LDS scratch (8B-chunk XOR swizzle, no barrier needed — producer ==
// consumer); PV over the wave's own 32 j x FULL 256 d (oacc 2x16 frags).
// Partial oacc/den merged across jhalf pairs once at the end via the K/V LDS.
// 2 barriers per j-tile (staging only).
// ---------------------------------------------------------------------------
__global__ __launch_bounds__(256, 2) void pass2_kernel(
    const ushort_t* __restrict__ q_ws, const ushort_t* __restrict__ k_ws,
    const ushort_t* __restrict__ vt_ws, const float* __restrict__ rz_ws,
    ushort_t* __restrict__ attn_out)
{
    __shared__ ushort_t smem[36864];          // 72 KB
    ushort_t* Kt = smem;                      // [64][256] swizzled (32 KB)
    ushort_t* Vt = smem + 16384;              // [256][64] swizzled (32 KB)
    ushort_t* Wt = smem + 32768;              // 4 x wave-private [32 i][32 j] (8 KB)

    const float SCALE = 0.0625f;
    const int tid  = threadIdx.x;
    const int wave = tid >> 6;
    const int lane = tid & 63;
    const int quad = lane >> 4;
    const int l15  = lane & 15;
    const int ihalf = wave >> 1;
    const int jhalf = wave & 1;

    const int g  = blockIdx.x;
    const int bh = ((g >> 8) << 3) | (g & 7);
    const int it = 31 - ((g >> 3) & 31);      // heavy blocks dispatched first
    const int b = bh >> 3, h = bh & 7;
    const int i0 = it * 64;

    const size_t qkbase = (size_t)b * 2048 * 2048 + (size_t)h * 256;

    bf16x8 qf[2][8];
#pragma unroll
    for (int ng = 0; ng < 2; ++ng) {
        const int i_l = ihalf * 32 + ng * 16 + l15;
        const ushort_t* qr = q_ws + qkbase + (size_t)(i0 + i_l) * 2048;
#pragma unroll
        for (int ks = 0; ks < 8; ++ks)
            qf[ng][ks] = *(const bf16x8*)(qr + ks * 32 + quad * 8);
    }

    float rzrow[2];
#pragma unroll
    for (int ng = 0; ng < 2; ++ng) {
        const int i_l = ihalf * 32 + ng * 16 + l15;
        rzrow[ng] = rz_ws[(size_t)bh * 2048 + i0 + i_l];
    }

    f32x4 oacc[2][16];
#pragma unroll
    for (int ng = 0; ng < 2; ++ng)
#pragma unroll
        for (int nf = 0; nf < 16; ++nf)
#pragma unroll
            for (int r = 0; r < 4; ++r) oacc[ng][nf][r] = 0.f;
    float den[2] = {0.f, 0.f};

    ushort_t* Wp = Wt + wave * 1024;          // wave-private w scratch

    for (int jt = 0; jt <= it; ++jt) {
        const int j0 = jt * 64;
        const bool diag = (jt == it);
        __syncthreads();
        {
            const ushort_t* kb = k_ws + qkbase + (size_t)j0 * 2048;
#pragma unroll
            for (int t = 0; t < 8; ++t) {
                const int row = wave * 16 + t * 2 + (lane >> 5);
                const int c = (lane & 31) ^ (row & 7);
                async16(kb + (size_t)row * 2048 + c * 8,
                        Kt + (wave * 16 + t * 2) * 256 + lane * 8);
            }
            const ushort_t* vb = vt_ws + (size_t)bh * 256 * 2048 + j0;
#pragma unroll
            for (int t = 0; t < 8; ++t) {
                const int row = wave * 64 + t * 8 + (lane >> 3);
                const int c = (lane & 7) ^ (row & 7);
                async16(vb + (size_t)row * 2048 + c * 8,
                        Vt + (wave * 64 + t * 8) * 64 + lane * 8);
            }
        }
        __syncthreads();

        // fully-masked quadrant on the diagonal tile: skip compute
        if (diag && ihalf == 0 && jhalf == 1) continue;

        f32x4 sacc[2][2];
#pragma unroll
        for (int a = 0; a < 2; ++a)
#pragma unroll
            for (int c = 0; c < 2; ++c)
#pragma unroll
                for (int r = 0; r < 4; ++r) sacc[a][c][r] = 0.f;

#pragma unroll
        for (int ks = 0; ks < 8; ++ks) {
            bf16x8 af[2];
#pragma unroll
            for (int mg = 0; mg < 2; ++mg) {
                const int j_l = jhalf * 32 + mg * 16 + l15;
                const int c = (ks * 4 + quad) ^ (j_l & 7);
                af[mg] = *(const bf16x8*)(Kt + j_l * 256 + c * 8);
            }
#pragma unroll
            for (int mg = 0; mg < 2; ++mg)
#pragma unroll
                for (int ng = 0; ng < 2; ++ng)
                    sacc[mg][ng] = __builtin_amdgcn_mfma_f32_16x16x32_bf16(
                        af[mg], qf[ng][ks], sacc[mg][ng], 0, 0, 0);
        }

        // w = exp(exp(s/16)*rz) with causal mask; write into wave-private Wt
#pragma unroll
        for (int mg = 0; mg < 2; ++mg) {
#pragma unroll
            for (int ng = 0; ng < 2; ++ng) {
                const int i_l = ihalf * 32 + ng * 16 + l15;   // tile-local i
                const int jb = jhalf * 32 + mg * 16 + quad * 4; // tile-local j
                us4 wp;
#pragma unroll
                for (int r = 0; r < 4; ++r) {
                    const float p = __expf(sacc[mg][ng][r] * SCALE) * rzrow[ng];
                    float w = __expf(p);
                    if (diag && (jb + r > i_l)) w = 0.f;
                    den[ng] += w;
                    wp[r] = f2bf(w);
                }
                const int row = ng * 16 + l15;                // wave-local i (0..31)
                const int ch = (mg * 4 + quad) ^ (row & 7);   // 8B-chunk swizzle
                *(us4*)(Wp + row * 32 + ch * 4) = wp;
            }
        }
        // same-wave consumer: no barrier, lgkmcnt ordering suffices

        // PV: oacc[32 i][256 d] += w(own 32 j) x Vt
#pragma unroll
        for (int ng = 0; ng < 2; ++ng) {
            const int row = ng * 16 + l15;
            const int sw = row & 7;
            const s16x4 lo = *(const s16x4*)(Wp + row * 32 + ((quad * 2) ^ sw) * 4);
            const s16x4 hi = *(const s16x4*)(Wp + row * 32 + ((quad * 2 + 1) ^ sw) * 4);
            union { s16x4 h[2]; bf16x8 v; } u;
            u.h[0] = lo; u.h[1] = hi;
            const bf16x8 aw = u.v;
#pragma unroll
            for (int nf = 0; nf < 16; ++nf) {
                const int d = nf * 16 + l15;
                const int c = (jhalf * 4 + quad) ^ (d & 7);
                const bf16x8 bv = *(const bf16x8*)(Vt + d * 64 + c * 8);
                oacc[ng][nf] = __builtin_amdgcn_mfma_f32_16x16x32_bf16(
                    aw, bv, oacc[ng][nf], 0, 0, 0);
            }
        }
    }

    // ---------------- epilogue: merge jhalf partials, scale, store ----------
#pragma unroll
    for (int ng = 0; ng < 2; ++ng) {
        den[ng] += __shfl_xor(den[ng], 16);
        den[ng] += __shfl_xor(den[ng], 32);
    }
    __syncthreads();                           // K/V tiles dead; reuse as merge buf
    float* mergeb = (float*)smem;              // 16384 f32 (64 KB): [ihalf][32 frag][256]
    float* dbuf   = (float*)(smem + 32768);    // 128 f32 den buffer (Wt region)
    if (quad == 0) {
#pragma unroll
        for (int ng = 0; ng < 2; ++ng)
            dbuf[(jhalf * 2 + ihalf) * 32 + ng * 16 + l15] = den[ng];
    }
    if (jhalf == 1) {
        float* mb = mergeb + ihalf * 8192;
#pragma unroll
        for (int ng = 0; ng < 2; ++ng)
#pragma unroll
            for (int nf = 0; nf < 16; ++nf)
                *(f32x4*)(mb + (ng * 16 + nf) * 256 + lane * 4) = oacc[ng][nf];
    }
    __syncthreads();
    if (jhalf == 0) {
        const float* mb = mergeb + ihalf * 8192;
#pragma unroll
        for (int ng = 0; ng < 2; ++ng)
#pragma unroll
            for (int nf = 0; nf < 16; ++nf) {
                const f32x4 o = *(const f32x4*)(mb + (ng * 16 + nf) * 256 + lane * 4);
#pragma unroll
                for (int r = 0; r < 4; ++r) oacc[ng][nf][r] += o[r];
            }
#pragma unroll
        for (int ng = 0; ng < 2; ++ng) {
#pragma unroll
            for (int r = 0; r < 4; ++r) {
                const int il32 = ng * 16 + quad * 4 + r;
                const float dt = dbuf[ihalf * 32 + il32] + dbuf[(2 + ihalf) * 32 + il32];
                const float rd = 1.0f / dt;
                const int i_t = ihalf * 32 + il32;
                ushort_t* orow = attn_out + qkbase + (size_t)(i0 + i_t) * 2048;
#pragma unroll
                for (int nf = 0; nf < 16; ++nf)
                    orow[nf * 16 + l15] = f2bf(oacc[ng][nf][r] * rd);
            }
        }
    }
}

// ---------------------------------------------------------------------------
extern "C" void kernel_launch(void* const* d_in, const int* in_sizes, int n_in,
                              void* d_out, int out_size, void* d_ws, size_t ws_size,
                              hipStream_t stream) {
    const float* x  = (const float*)d_in[0];
    const float* Wq = (const float*)d_in[1];
    const float* Wk = (const float*)d_in[2];
    const float* Wv = (const float*)d_in[3];
    const float* Wo = (const float*)d_in[4];

    char* ws = (char*)d_ws;
    ushort_t* xb    = (ushort_t*)(ws);
    ushort_t* wqb   = (ushort_t*)(ws + 4194304);   // wq/wk/wv contiguous -> [6144][256]
    ushort_t* wkb   = (ushort_t*)(ws + 5242880);
    ushort_t* wvb   = (ushort_t*)(ws + 6291456);
    ushort_t* wob   = (ushort_t*)(ws + 7340032);
    ushort_t* q_ws  = (ushort_t*)(ws + 8388608);
    ushort_t* k_ws  = (ushort_t*)(ws + 41943040);
    ushort_t* vt_ws = (ushort_t*)(ws + 75497472);
    ushort_t* ao_ws = (ushort_t*)(ws + 109051904);
    float*    rz_ws = (float*)   (ws + 142606336);

    convert_kernel<<<4096, 256, 0, stream>>>(x, Wq, Wk, Wv, Wo, xb, wqb, wkb, wvb, wob);

    // fused Q/K/V projection: one GEMM over the concatenated weight
    gemm_bt_kernel<3><<<dim3(64, 48), 256, 0, stream>>>(
        xb, wqb, q_ws, k_ws, vt_ws, 8192, 6144, 256);

    pass1_kernel<<<1024, 256, 0, stream>>>(q_ws, k_ws, rz_ws);
    pass2_kernel<<<1024, 256, 0, stream>>>(q_ws, k_ws, vt_ws, rz_ws, ao_ws);

    gemm_out_kernel<<<dim3(128, 2), 256, 0, stream>>>(ao_ws, wob, (float*)d_out);
}

// Round 4
// 370.360 us; speedup vs baseline: 2.3121x; 2.3121x over previous
//
#include <hip/hip_runtime.h>
#include <stdint.h>

typedef unsigned short ushort_t;
typedef __attribute__((ext_vector_type(8))) short bf16x8;
typedef __attribute__((ext_vector_type(4))) short s16x4;
typedef __attribute__((ext_vector_type(4))) float f32x4;
typedef __attribute__((ext_vector_type(4))) unsigned short us4;

#define DEV __device__ __forceinline__

DEV ushort_t f2bf(float f) {
    unsigned int u = __float_as_uint(f);
    u += 0x7fffu + ((u >> 16) & 1u);
    return (ushort_t)(u >> 16);
}

DEV void async16(const ushort_t* g, ushort_t* l) {
    __builtin_amdgcn_global_load_lds(
        (const __attribute__((address_space(1))) void*)g,
        (__attribute__((address_space(3))) void*)l,
        16, 0, 0);
}

// ---------------------------------------------------------------------------
// f32 -> bf16 conversion of x and the four weight matrices (one launch).
// ---------------------------------------------------------------------------
__global__ void convert_kernel(const float* __restrict__ x, const float* __restrict__ wq,
                               const float* __restrict__ wk, const float* __restrict__ wv,
                               const float* __restrict__ wo,
                               ushort_t* __restrict__ xb, ushort_t* __restrict__ wqb,
                               ushort_t* __restrict__ wkb, ushort_t* __restrict__ wvb,
                               ushort_t* __restrict__ wob)
{
    const int i = blockIdx.x * 256 + threadIdx.x; // float4 index, 1048576 total
    const float* src; ushort_t* dst; int off;
    if (i < 524288)      { src = x;  dst = xb;  off = i; }
    else if (i < 655360) { src = wq; dst = wqb; off = i - 524288; }
    else if (i < 786432) { src = wk; dst = wkb; off = i - 655360; }
    else if (i < 917504) { src = wv; dst = wvb; off = i - 786432; }
    else                 { src = wo; dst = wob; off = i - 917504; }
    const float4 v = ((const float4*)src)[off];
    us4 o;
    o[0] = f2bf(v.x); o[1] = f2bf(v.y); o[2] = f2bf(v.z); o[3] = f2bf(v.w);
    ((us4*)dst)[off] = o;
}

// ---------------------------------------------------------------------------
// Fused QKV projection GEMM: C = x[8192][256] * Wqkv[6144][256]^T,
// 128x128 tile, 4 waves. Column block routes to q / k (row-major) or v
// (transposed [b][h][d][l]).
// ---------------------------------------------------------------------------
__global__ __launch_bounds__(256, 2) void gemm_qkv_kernel(
    const ushort_t* __restrict__ A, const ushort_t* __restrict__ Bm,
    void* __restrict__ C0, void* __restrict__ C1, void* __restrict__ C2)
{
    __shared__ ushort_t At[128 * 64];
    __shared__ ushort_t Bt[128 * 64];

    const int tid  = threadIdx.x;
    const int wave = tid >> 6;
    const int lane = tid & 63;
    const int quad = lane >> 4;
    const int l15  = lane & 15;
    const int mhalf = wave >> 1;
    const int nhalf = wave & 1;
    const int m0 = blockIdx.x * 128;
    const int n0 = blockIdx.y * 128;
    const int K = 256;

    f32x4 acc[4][4];
#pragma unroll
    for (int mf = 0; mf < 4; ++mf)
#pragma unroll
        for (int nf = 0; nf < 4; ++nf)
#pragma unroll
            for (int r = 0; r < 4; ++r) acc[mf][nf][r] = 0.f;

    const int crow = (lane & 7) ^ (lane >> 3);

    for (int k0 = 0; k0 < K; k0 += 64) {
        __syncthreads();
#pragma unroll
        for (int t = 0; t < 4; ++t) {
            const int row = wave * 32 + t * 8 + (lane >> 3);
            async16(A + (size_t)(m0 + row) * K + k0 + crow * 8,
                    At + (wave * 32 + t * 8) * 64 + lane * 8);
            async16(Bm + (size_t)(n0 + row) * K + k0 + crow * 8,
                    Bt + (wave * 32 + t * 8) * 64 + lane * 8);
        }
        __syncthreads();
#pragma unroll
        for (int ks = 0; ks < 2; ++ks) {
            bf16x8 af[4], bf[4];
#pragma unroll
            for (int mf = 0; mf < 4; ++mf) {
                const int ml = mhalf * 64 + mf * 16 + l15;
                const int c = (ks * 4 + quad) ^ (ml & 7);
                af[mf] = *(const bf16x8*)(At + ml * 64 + c * 8);
            }
#pragma unroll
            for (int nf = 0; nf < 4; ++nf) {
                const int nl = nhalf * 64 + nf * 16 + l15;
                const int c = (ks * 4 + quad) ^ (nl & 7);
                bf[nf] = *(const bf16x8*)(Bt + nl * 64 + c * 8);
            }
#pragma unroll
            for (int mf = 0; mf < 4; ++mf)
#pragma unroll
                for (int nf = 0; nf < 4; ++nf)
                    acc[mf][nf] = __builtin_amdgcn_mfma_f32_16x16x32_bf16(
                        af[mf], bf[nf], acc[mf][nf], 0, 0, 0);
        }
    }

    const int sel = n0 >> 11;               // 0:q 1:k 2:v
    if (sel == 2) {
#pragma unroll
        for (int mf = 0; mf < 4; ++mf)
#pragma unroll
            for (int nf = 0; nf < 4; ++nf) {
                const int row = m0 + mhalf * 64 + mf * 16 + quad * 4;
                const int colv = (n0 - 4096) + nhalf * 64 + nf * 16 + l15;
                const int b_ = row >> 11, l_ = row & 2047;
                const int h_ = colv >> 8, d_ = colv & 255;
                us4 pk;
#pragma unroll
                for (int r = 0; r < 4; ++r) pk[r] = f2bf(acc[mf][nf][r]);
                *(us4*)((ushort_t*)C2 +
                        (((size_t)(b_ * 8 + h_) * 256 + d_) * 2048 + l_)) = pk;
            }
    } else {
        ushort_t* dst = sel ? (ushort_t*)C1 : (ushort_t*)C0;
#pragma unroll
        for (int mf = 0; mf < 4; ++mf)
#pragma unroll
            for (int nf = 0; nf < 4; ++nf)
#pragma unroll
                for (int r = 0; r < 4; ++r) {
                    const int row = m0 + mhalf * 64 + mf * 16 + quad * 4 + r;
                    const int col = (n0 & 2047) + nhalf * 64 + nf * 16 + l15;
                    dst[(size_t)row * 2048 + col] = f2bf(acc[mf][nf][r]);
                }
    }
}

// ---------------------------------------------------------------------------
// Output projection GEMM, 64x128 tile (grid 128x2 = 256 blocks -> all CUs).
// C[8192][256] f32 = ao[8192][2048] * Wo[256][2048]^T
// ---------------------------------------------------------------------------
__global__ __launch_bounds__(256, 4) void gemm_out_kernel(
    const ushort_t* __restrict__ A, const ushort_t* __restrict__ Bm,
    float* __restrict__ C)
{
    __shared__ ushort_t At[64 * 64];    // 8 KB
    __shared__ ushort_t Bt[128 * 64];   // 16 KB

    const int tid  = threadIdx.x;
    const int wave = tid >> 6;
    const int lane = tid & 63;
    const int quad = lane >> 4;
    const int l15  = lane & 15;
    const int mhalf = wave >> 1;
    const int nhalf = wave & 1;
    const int m0 = blockIdx.x * 64;
    const int n0 = blockIdx.y * 128;

    f32x4 acc[2][4];
#pragma unroll
    for (int mf = 0; mf < 2; ++mf)
#pragma unroll
        for (int nf = 0; nf < 4; ++nf)
#pragma unroll
            for (int r = 0; r < 4; ++r) acc[mf][nf][r] = 0.f;

    const int crow = (lane & 7) ^ (lane >> 3);

    for (int k0 = 0; k0 < 2048; k0 += 64) {
        __syncthreads();
#pragma unroll
        for (int t = 0; t < 2; ++t) {
            const int row = wave * 16 + t * 8 + (lane >> 3);
            async16(A + (size_t)(m0 + row) * 2048 + k0 + crow * 8,
                    At + (wave * 16 + t * 8) * 64 + lane * 8);
        }
#pragma unroll
        for (int t = 0; t < 4; ++t) {
            const int row = wave * 32 + t * 8 + (lane >> 3);
            async16(Bm + (size_t)(n0 + row) * 2048 + k0 + crow * 8,
                    Bt + (wave * 32 + t * 8) * 64 + lane * 8);
        }
        __syncthreads();
#pragma unroll
        for (int ks = 0; ks < 2; ++ks) {
            bf16x8 af[2], bf[4];
#pragma unroll
            for (int mf = 0; mf < 2; ++mf) {
                const int ml = mhalf * 32 + mf * 16 + l15;
                const int c = (ks * 4 + quad) ^ (ml & 7);
                af[mf] = *(const bf16x8*)(At + ml * 64 + c * 8);
            }
#pragma unroll
            for (int nf = 0; nf < 4; ++nf) {
                const int nl = nhalf * 64 + nf * 16 + l15;
                const int c = (ks * 4 + quad) ^ (nl & 7);
                bf[nf] = *(const bf16x8*)(Bt + nl * 64 + c * 8);
            }
#pragma unroll
            for (int mf = 0; mf < 2; ++mf)
#pragma unroll
                for (int nf = 0; nf < 4; ++nf)
                    acc[mf][nf] = __builtin_amdgcn_mfma_f32_16x16x32_bf16(
                        af[mf], bf[nf], acc[mf][nf], 0, 0, 0);
        }
    }

#pragma unroll
    for (int mf = 0; mf < 2; ++mf)
#pragma unroll
        for (int nf = 0; nf < 4; ++nf)
#pragma unroll
            for (int r = 0; r < 4; ++r) {
                const int row = m0 + mhalf * 32 + mf * 16 + quad * 4 + r;
                const int col = n0 + nhalf * 64 + nf * 16 + l15;
                C[(size_t)row * 256 + col] = acc[mf][nf][r];
            }
}

// ---------------------------------------------------------------------------
// Pass 1: full-row softmax denominator Z_i = sum_j exp(s_ij/16).
// ---------------------------------------------------------------------------
__global__ __launch_bounds__(256, 4) void pass1_kernel(
    const ushort_t* __restrict__ q_ws, const ushort_t* __restrict__ k_ws,
    float* __restrict__ rz_ws)
{
    __shared__ ushort_t Kt[64 * 256];   // 32 KB, chunk-swizzled
    __shared__ float zred[2][64];

    const float SCALE = 0.0625f;        // 1/sqrt(256)
    const int tid  = threadIdx.x;
    const int wave = tid >> 6;
    const int lane = tid & 63;
    const int quad = lane >> 4;
    const int l15  = lane & 15;
    const int ihalf = wave >> 1;
    const int jhalf = wave & 1;

    const int g  = blockIdx.x;
    const int bh = ((g >> 8) << 3) | (g & 7);
    const int it = (g >> 3) & 31;
    const int b = bh >> 3, h = bh & 7;
    const int i0 = it * 64;

    const size_t qkbase = (size_t)b * 2048 * 2048 + (size_t)h * 256;

    bf16x8 qf[2][8];
#pragma unroll
    for (int ng = 0; ng < 2; ++ng) {
        const int i_l = ihalf * 32 + ng * 16 + l15;
        const ushort_t* qr = q_ws + qkbase + (size_t)(i0 + i_l) * 2048;
#pragma unroll
        for (int ks = 0; ks < 8; ++ks)
            qf[ng][ks] = *(const bf16x8*)(qr + ks * 32 + quad * 8);
    }

    float z[2] = {0.f, 0.f};

    for (int jt = 0; jt < 32; ++jt) {
        const int j0 = jt * 64;
        __syncthreads();
        {
            const ushort_t* kb = k_ws + qkbase + (size_t)j0 * 2048;
#pragma unroll
            for (int t = 0; t < 8; ++t) {
                const int row = wave * 16 + t * 2 + (lane >> 5);
                const int c = (lane & 31) ^ (row & 7);
                async16(kb + (size_t)row * 2048 + c * 8,
                        Kt + (wave * 16 + t * 2) * 256 + lane * 8);
            }
        }
        __syncthreads();

        f32x4 sacc[2][2];
#pragma unroll
        for (int a = 0; a < 2; ++a)
#pragma unroll
            for (int c = 0; c < 2; ++c)
#pragma unroll
                for (int r = 0; r < 4; ++r) sacc[a][c][r] = 0.f;

#pragma unroll
        for (int ks = 0; ks < 8; ++ks) {
            bf16x8 af[2];
#pragma unroll
            for (int mg = 0; mg < 2; ++mg) {
                const int j_l = jhalf * 32 + mg * 16 + l15;
                const int c = (ks * 4 + quad) ^ (j_l & 7);
                af[mg] = *(const bf16x8*)(Kt + j_l * 256 + c * 8);
            }
#pragma unroll
            for (int mg = 0; mg < 2; ++mg)
#pragma unroll
                for (int ng = 0; ng < 2; ++ng)
                    sacc[mg][ng] = __builtin_amdgcn_mfma_f32_16x16x32_bf16(
                        af[mg], qf[ng][ks], sacc[mg][ng], 0, 0, 0);
        }

#pragma unroll
        for (int ng = 0; ng < 2; ++ng)
#pragma unroll
            for (int mg = 0; mg < 2; ++mg)
#pragma unroll
                for (int r = 0; r < 4; ++r)
                    z[ng] += __expf(sacc[mg][ng][r] * SCALE);
    }

#pragma unroll
    for (int ng = 0; ng < 2; ++ng) {
        z[ng] += __shfl_xor(z[ng], 16);
        z[ng] += __shfl_xor(z[ng], 32);
    }
    __syncthreads();
    if (quad == 0) {
#pragma unroll
        for (int ng = 0; ng < 2; ++ng) {
            const int i_l = ihalf * 32 + ng * 16 + l15;
            zred[jhalf][i_l] = z[ng];
        }
    }
    __syncthreads();
    if (tid < 64)
        rz_ws[(size_t)bh * 2048 + i0 + tid] = 1.0f / (zred[0][tid] + zred[1][tid]);
}

// ---------------------------------------------------------------------------
// Pass 2: causal w = exp(p), p = exp(s/16)/Z; PV accumulate; divide by sum(w).
// Wave w owns i-rows [w*16, w*16+16) x ALL 64 j x ALL 256 d:
//   QK: 4 K A-frags x 1 Q B-frag (qf = 32 VGPR); w -> wave-private 2 KB LDS
//   ([16 i][64 j], XOR-16 chunk swizzle, conflict-free both sides, no barrier
//   -- producer == consumer, DS in-order per wave); PV: oacc[16] = 64 VGPR.
// No cross-wave merge; 2 barriers/tile (staging only). Diag tile: wave w
// computes only mg<=w (QK) / ks<=w>>1 (PV), zero-fills skipped w chunks.
// ---------------------------------------------------------------------------
__global__ __launch_bounds__(256, 2) void pass2_kernel(
    const ushort_t* __restrict__ q_ws, const ushort_t* __restrict__ k_ws,
    const ushort_t* __restrict__ vt_ws, const float* __restrict__ rz_ws,
    ushort_t* __restrict__ attn_out)
{
    __shared__ ushort_t smem[36864];          // 72 KB
    ushort_t* Kt = smem;                      // [64 j][256 d] swizzled (32 KB)
    ushort_t* Vt = smem + 16384;              // [256 d][64 j] swizzled (32 KB)
    ushort_t* Wt = smem + 32768;              // 4 x wave-private [16 i][64 j] (8 KB)

    const float SCALE = 0.0625f;
    const int tid  = threadIdx.x;
    const int wave = tid >> 6;
    const int lane = tid & 63;
    const int quad = lane >> 4;
    const int l15  = lane & 15;

    const int g  = blockIdx.x;
    const int bh = ((g >> 8) << 3) | (g & 7);
    const int it = 31 - ((g >> 3) & 31);      // heavy blocks dispatched first
    const int b = bh >> 3, h = bh & 7;
    const int i0 = it * 64;

    const size_t qkbase = (size_t)b * 2048 * 2048 + (size_t)h * 256;

    // Q B-operand frags for this wave's 16 rows: i = wave*16 + l15
    bf16x8 qf[8];
    {
        const ushort_t* qr = q_ws + qkbase + (size_t)(i0 + wave * 16 + l15) * 2048;
#pragma unroll
        for (int ks = 0; ks < 8; ++ks)
            qf[ks] = *(const bf16x8*)(qr + ks * 32 + quad * 8);
    }
    const float rz = rz_ws[(size_t)bh * 2048 + i0 + wave * 16 + l15];

    f32x4 oacc[16];
#pragma unroll
    for (int nf = 0; nf < 16; ++nf)
#pragma unroll
        for (int r = 0; r < 4; ++r) oacc[nf][r] = 0.f;
    float den = 0.f;

    ushort_t* Wp = Wt + wave * 1024;          // wave-private w scratch

    for (int jt = 0; jt <= it; ++jt) {
        const int j0 = jt * 64;
        const bool diag = (jt == it);
        __syncthreads();
        {
            const ushort_t* kb = k_ws + qkbase + (size_t)j0 * 2048;
#pragma unroll
            for (int t = 0; t < 8; ++t) {
                const int row = wave * 16 + t * 2 + (lane >> 5);
                const int c = (lane & 31) ^ (row & 7);
                async16(kb + (size_t)row * 2048 + c * 8,
                        Kt + (wave * 16 + t * 2) * 256 + lane * 8);
            }
            const ushort_t* vb = vt_ws + (size_t)bh * 256 * 2048 + j0;
#pragma unroll
            for (int t = 0; t < 8; ++t) {
                const int row = wave * 64 + t * 8 + (lane >> 3);
                const int c = (lane & 7) ^ (row & 7);
                async16(vb + (size_t)row * 2048 + c * 8,
                        Vt + (wave * 64 + t * 8) * 64 + lane * 8);
            }
        }
        __syncthreads();

        const int mgmax = diag ? wave : 3;

        f32x4 sacc[4];
#pragma unroll
        for (int mg = 0; mg < 4; ++mg)
#pragma unroll
            for (int r = 0; r < 4; ++r) sacc[mg][r] = 0.f;

#pragma unroll
        for (int ks = 0; ks < 8; ++ks) {
#pragma unroll
            for (int mg = 0; mg < 4; ++mg) {
                if (mg > mgmax) continue;     // wave-uniform branch
                const int c = (ks * 4 + quad) ^ (l15 & 7);
                const bf16x8 af = *(const bf16x8*)(Kt + (mg * 16 + l15) * 256 + c * 8);
                sacc[mg] = __builtin_amdgcn_mfma_f32_16x16x32_bf16(
                    af, qf[ks], sacc[mg], 0, 0, 0);
            }
        }

        // w = exp(exp(s/16)*rz), causal mask on diag; -> wave-private Wt
#pragma unroll
        for (int mg = 0; mg < 4; ++mg) {
            us4 wp;
            if (mg <= mgmax) {
#pragma unroll
                for (int r = 0; r < 4; ++r) {
                    const float p = __expf(sacc[mg][r] * SCALE) * rz;
                    float w = __expf(p);
                    if (diag && (mg * 16 + quad * 4 + r > wave * 16 + l15)) w = 0.f;
                    den += w;
                    wp[r] = f2bf(w);
                }
            } else {
                wp[0] = 0; wp[1] = 0; wp[2] = 0; wp[3] = 0;
            }
            const int c = (mg * 4 + quad) ^ l15;          // 4-bit XOR swizzle
            *(us4*)(Wp + l15 * 64 + c * 4) = wp;
        }
        // same-wave consumer: DS ops are in-order per wave, no barrier

        // PV: oacc[16 i][256 d] += w(all 64 j) x Vt
        const int ksmax = diag ? (wave >> 1) : 1;
#pragma unroll
        for (int ks = 0; ks < 2; ++ks) {
            if (ks > ksmax) continue;
            const s16x4 lo = *(const s16x4*)(Wp + l15 * 64 + ((ks * 8 + quad * 2)     ^ l15) * 4);
            const s16x4 hi = *(const s16x4*)(Wp + l15 * 64 + ((ks * 8 + quad * 2 + 1) ^ l15) * 4);
            union { s16x4 h[2]; bf16x8 v; } u;
            u.h[0] = lo; u.h[1] = hi;
            const bf16x8 aw = u.v;
#pragma unroll
            for (int nf = 0; nf < 16; ++nf) {
                const int d = nf * 16 + l15;
                const int c = (ks * 4 + quad) ^ (d & 7);
                const bf16x8 bv = *(const bf16x8*)(Vt + d * 64 + c * 8);
                oacc[nf] = __builtin_amdgcn_mfma_f32_16x16x32_bf16(
                    aw, bv, oacc[nf], 0, 0, 0);
            }
        }
    }

    // ---------------- epilogue: wave-local den transpose, scale, store ------
    den += __shfl_xor(den, 16);
    den += __shfl_xor(den, 32);               // all lanes: den for row i=l15
    if (quad == 0) ((float*)Wp)[l15] = den;   // same-wave DS in-order
    const float* dW = (const float*)Wp;
#pragma unroll
    for (int r = 0; r < 4; ++r) {
        const int il = quad * 4 + r;
        const float rd = 1.0f / dW[il];
        ushort_t* orow = attn_out + qkbase + (size_t)(i0 + wave * 16 + il) * 2048;
#pragma unroll
        for (int nf = 0; nf < 16; ++nf)
            orow[nf * 16 + l15] = f2bf(oacc[nf][r] * rd);
    }
}

// ---------------------------------------------------------------------------
extern "C" void kernel_launch(void* const* d_in, const int* in_sizes, int n_in,
                              void* d_out, int out_size, void* d_ws, size_t ws_size,
                              hipStream_t stream) {
    const float* x  = (const float*)d_in[0];
    const float* Wq = (const float*)d_in[1];
    const float* Wk = (const float*)d_in[2];
    const float* Wv = (const float*)d_in[3];
    const float* Wo = (const float*)d_in[4];

    char* ws = (char*)d_ws;
    ushort_t* xb    = (ushort_t*)(ws);
    ushort_t* wqb   = (ushort_t*)(ws + 4194304);   // wq/wk/wv contiguous -> [6144][256]
    ushort_t* wkb   = (ushort_t*)(ws + 5242880);
    ushort_t* wvb   = (ushort_t*)(ws + 6291456);
    ushort_t* wob   = (ushort_t*)(ws + 7340032);
    ushort_t* q_ws  = (ushort_t*)(ws + 8388608);
    ushort_t* k_ws  = (ushort_t*)(ws + 41943040);
    ushort_t* vt_ws = (ushort_t*)(ws + 75497472);
    ushort_t* ao_ws = (ushort_t*)(ws + 109051904);
    float*    rz_ws = (float*)   (ws + 142606336);

    convert_kernel<<<4096, 256, 0, stream>>>(x, Wq, Wk, Wv, Wo, xb, wqb, wkb, wvb, wob);

    gemm_qkv_kernel<<<dim3(64, 48), 256, 0, stream>>>(xb, wqb, q_ws, k_ws, vt_ws);

    pass1_kernel<<<1024, 256, 0, stream>>>(q_ws, k_ws, rz_ws);
    pass2_kernel<<<1024, 256, 0, stream>>>(q_ws, k_ws, vt_ws, rz_ws, ao_ws);

    gemm_out_kernel<<<dim3(128, 2), 256, 0, stream>>>(ao_ws, wob, (float*)d_out);
}